// Round 1
// baseline (174.853 us; speedup 1.0000x reference)
//
#include <hip/hip_runtime.h>
#include <hip/hip_bf16.h>

#define LOG2PI_F 1.8378770664093453f

typedef float f32x4 __attribute__((ext_vector_type(4)));
typedef short s16x8 __attribute__((ext_vector_type(8)));

// ---- workspace layout (float offsets into d_ws) ----
#define OFF_PREC   0        // f32 [8][16][16]
#define OFF_LOGDET 2048     // f32 [8]
#define OFF_LTR    2064     // f32 [8][8]   log(softmax(T)+1e-8)
#define OFF_LINI   2128     // f32 [8]      log softmax(init)
#define OFF_CHAIN  2144     // int [8][16]  state chain table
#define OFF_S0     2304     // int [512]    argmax state per batch
#define OFF_ELL    4096     // f32 [128][512][8]  emis_ll[f][b][s]
#define OFF_WT     528384   // ushort(bf16) [8][128][16][16]  Wt[s][l][d][c]

__device__ inline unsigned short f2bf(float x) {
  union { float f; unsigned u; } v; v.f = x;
  unsigned r = v.u + 0x7fffu + ((v.u >> 16) & 1u);  // RNE
  return (unsigned short)(r >> 16);
}

// ---------------------------------------------------------------------------
// prep: per-state covariance -> prec/logdet; log_trans; log_init; chain table
// ---------------------------------------------------------------------------
__global__ __launch_bounds__(256) void prep_kernel(const float* __restrict__ tmat,
                                                   const float* __restrict__ initd,
                                                   const float* __restrict__ cc,
                                                   float* __restrict__ ws) {
  __shared__ float L[8][16][16];
  __shared__ float Cv[8][16][16];
  int t = threadIdx.x;
  float* prec   = ws + OFF_PREC;
  float* logdet = ws + OFF_LOGDET;
  float* ltr    = ws + OFF_LTR;
  float* lini   = ws + OFF_LINI;
  int*   chain  = (int*)(ws + OFF_CHAIN);

  if (t < 8) {
    int s = t;
    const float* c0 = cc + s * 256;
    // chol = tril(cc,-1) + diag(exp(diag(cc)))
    for (int i = 0; i < 16; ++i)
      for (int j = 0; j < 16; ++j) {
        float v = c0[i * 16 + j];
        L[s][i][j] = (i > j) ? v : (i == j ? expf(v) : 0.f);
      }
    // covar = chol@chol^T + 1e-6 I (lower+mirror)
    for (int i = 0; i < 16; ++i)
      for (int j = 0; j <= i; ++j) {
        float sum = (i == j) ? 1e-6f : 0.f;
        for (int k = 0; k <= j; ++k) sum += L[s][i][k] * L[s][j][k];
        Cv[s][i][j] = sum; Cv[s][j][i] = sum;
      }
    // cholesky of covar into L (lower)
    for (int j = 0; j < 16; ++j) {
      float dv = Cv[s][j][j];
      for (int k = 0; k < j; ++k) dv -= L[s][j][k] * L[s][j][k];
      dv = sqrtf(dv);
      L[s][j][j] = dv;
      for (int i = j + 1; i < 16; ++i) {
        float v = Cv[s][i][j];
        for (int k = 0; k < j; ++k) v -= L[s][i][k] * L[s][j][k];
        L[s][i][j] = v / dv;
      }
    }
    float ld = 0.f;
    for (int j = 0; j < 16; ++j) ld += logf(L[s][j][j]);
    logdet[s] = 2.f * ld;
  } else if (t == 8) {
    float m = -1e30f;
    for (int i = 0; i < 8; ++i) m = fmaxf(m, initd[i]);
    float sum = 0.f;
    for (int i = 0; i < 8; ++i) sum += expf(initd[i] - m);
    float ls = logf(sum);
    for (int i = 0; i < 8; ++i) lini[i] = initd[i] - m - ls;
  } else if (t == 9) {
    // deterministic argmax-transition chain (softmax is monotone -> raw row argmax)
    int nxt[8];
    for (int i = 0; i < 8; ++i) {
      float best = -1e30f; int bi = 0;
      for (int j = 0; j < 8; ++j) {
        float v = tmat[i * 8 + j];
        if (v > best) { best = v; bi = j; }   // strict > keeps first max (jnp rule)
      }
      nxt[i] = bi;
    }
    for (int s0 = 0; s0 < 8; ++s0) {
      int c = s0;
      for (int k = 0; k < 16; ++k) { c = nxt[c]; chain[s0 * 16 + k] = c; }
    }
  } else if (t >= 16 && t < 24) {
    int i = t - 16;
    float m = -1e30f;
    for (int j = 0; j < 8; ++j) m = fmaxf(m, tmat[i * 8 + j]);
    float sum = 0.f;
    for (int j = 0; j < 8; ++j) sum += expf(tmat[i * 8 + j] - m);
    for (int j = 0; j < 8; ++j)
      ltr[i * 8 + j] = logf(expf(tmat[i * 8 + j] - m) / sum + 1e-8f);
  }
  __syncthreads();
  // phase B: prec = inv(covar) via Lc solves, 128 threads = 8 states x 16 cols
  if (t < 128) {
    int s = t >> 4, col = t & 15;
    float y[16], x[16];
#pragma unroll
    for (int i = 0; i < 16; ++i) {
      float v = (i == col) ? 1.f : 0.f;
#pragma unroll
      for (int k = 0; k < 16; ++k) if (k < i) v -= L[s][i][k] * y[k];
      y[i] = v / L[s][i][i];
    }
#pragma unroll
    for (int i = 15; i >= 0; --i) {
      float v = y[i];
#pragma unroll
      for (int k = 0; k < 16; ++k) if (k > i) v -= L[s][k][i] * x[k];
      x[i] = v / L[s][i][i];
    }
#pragma unroll
    for (int i = 0; i < 16; ++i) prec[s * 256 + i * 16 + col] = x[i];
  }
}

// ---------------------------------------------------------------------------
// Wt: transpose W[s][l][c][d] f32 -> Wt[s][l][d][c] bf16 (B-fragment friendly)
// ---------------------------------------------------------------------------
__global__ __launch_bounds__(256) void wt_kernel(const float* __restrict__ W,
                                                 float* __restrict__ ws) {
  unsigned short* Wt = (unsigned short*)(ws + OFF_WT);
  __shared__ float tmp[256];
  int sl = blockIdx.x;              // s*128 + l
  int tid = threadIdx.x;
  tmp[tid] = W[sl * 256 + tid];     // coalesced read of one (s,l) slab
  __syncthreads();
  int d = tid >> 4, c = tid & 15;
  Wt[sl * 256 + tid] = f2bf(tmp[c * 16 + d]);   // out[d][c] = in[c][d]
}

// ---------------------------------------------------------------------------
// emis_ll: ar = einsum via MFMA bf16, then diff/quad -> ell[f][b][s]
// one block per (b,s); 4 waves; wave w owns M-tiles {w, 7-w} (72 MFMAs each)
// ---------------------------------------------------------------------------
__global__ __launch_bounds__(256) void emis_kernel(const float* __restrict__ emis,
                                                   const float* __restrict__ means,
                                                   float* __restrict__ ws) {
  const float* prec   = ws + OFF_PREC;
  const float* logdet = ws + OFF_LOGDET;
  const unsigned short* Wt = (const unsigned short*)(ws + OFF_WT);
  float* ell = ws + OFF_ELL;
  int b = blockIdx.x >> 3, s = blockIdx.x & 7;   // s==XCD round-robin -> Wt[s] L2-resident
  int tid = threadIdx.x;

  __shared__ unsigned short padh[2][256][8];   // zero-padded emis, split by c-half
  __shared__ float diffL[128][17];
  __shared__ float precS[256];

  precS[tid] = prec[s * 256 + tid];
  for (int idx = tid; idx < 2048; idx += 256) {        // zero rows 0..127 (both planes)
    int pl = idx >> 10, row = (idx >> 3) & 127, c = idx & 7;
    padh[pl][row][c] = 0;
  }
  for (int idx = tid; idx < 2048; idx += 256) {        // rows 128..255 = emissions
    int row = idx >> 4, c = idx & 15;
    padh[c >> 3][128 + row][c & 7] = f2bf(emis[(b << 11) + idx]);
  }
  __syncthreads();

  int wave = tid >> 6, lane = tid & 63;
  int m1 = wave, m2 = 7 - wave;
  int rc = lane & 15;            // A row within tile == B col (d)
  int h  = (lane >> 4) & 1;      // c half (0..7 / 8..15)
  int dl = lane >> 5;            // which l of the k-step (k=32 spans 2 lags)
  f32x4 acc1 = {0.f, 0.f, 0.f, 0.f}, acc2 = {0.f, 0.f, 0.f, 0.f};
  const unsigned short* Bbase = Wt + ((s * 128 + dl) * 16 + rc) * 16 + h * 8;
  int k1 = 56 - 8 * m1, k2 = 56 - 8 * m2;   // k2 <= k1

  for (int kk = k2; kk < 64; ++kk) {
    s16x8 bfrag = *(const s16x8*)(Bbase + kk * 512);
    int l = 2 * kk + dl;
    s16x8 a2f = *(const s16x8*)(&padh[h][16 * m2 + rc + l][0]);
    acc2 = __builtin_amdgcn_mfma_f32_16x16x32_bf16(a2f, bfrag, acc2, 0, 0, 0);
    if (kk >= k1) {
      s16x8 a1f = *(const s16x8*)(&padh[h][16 * m1 + rc + l][0]);
      acc1 = __builtin_amdgcn_mfma_f32_16x16x32_bf16(a1f, bfrag, acc1, 0, 0, 0);
    }
  }

  // C layout: col = lane&15, row = (lane>>4)*4 + r
  float mn = means[s * 16 + rc];
  int fb1 = 16 * m1 + ((lane >> 4) << 2);
  int fb2 = 16 * m2 + ((lane >> 4) << 2);
#pragma unroll
  for (int r = 0; r < 4; ++r) {
    int f1 = fb1 + r;
    diffL[f1][rc] = emis[(b << 11) + f1 * 16 + rc] - acc1[r] - mn;
    int f2 = fb2 + r;
    diffL[f2][rc] = emis[(b << 11) + f2 * 16 + rc] - acc2[r] - mn;
  }
  __syncthreads();

  // quad[f] = diff^T prec diff ; 2 threads per f
  int f = tid >> 1, hf = tid & 1;
  float q = 0.f;
  for (int c = hf * 8; c < hf * 8 + 8; ++c) {
    float dc = diffL[f][c];
    float tsum = 0.f;
#pragma unroll
    for (int dd = 0; dd < 16; ++dd) tsum += precS[c * 16 + dd] * diffL[f][dd];
    q += dc * tsum;
  }
  q += __shfl_xor(q, 1);
  if (hf == 0)
    ell[f * 4096 + b * 8 + s] = -0.5f * (q + logdet[s] + 16.f * LOG2PI_F);
}

// ---------------------------------------------------------------------------
// forward scan + argmax: thread per (b,s), 8-lane shuffle logsumexp
// ---------------------------------------------------------------------------
__global__ __launch_bounds__(256) void fwd_kernel(float* __restrict__ ws) {
  const float* ell  = ws + OFF_ELL;
  const float* ltr  = ws + OFF_LTR;
  const float* lini = ws + OFF_LINI;
  int* s0p = (int*)(ws + OFF_S0);
  int g = blockIdx.x * 256 + threadIdx.x;
  int b = g >> 3, s = g & 7;
  float ltc[8];
#pragma unroll
  for (int i = 0; i < 8; ++i) ltc[i] = ltr[i * 8 + s];
  float la = lini[s] + ell[b * 8 + s];
  for (int f = 1; f < 128; ++f) {
    float v[8], m = -1e30f;
#pragma unroll
    for (int i = 0; i < 8; ++i) {
      v[i] = __shfl(la, i, 8) + ltc[i];
      m = fmaxf(m, v[i]);
    }
    float sum = 0.f;
#pragma unroll
    for (int i = 0; i < 8; ++i) sum += expf(v[i] - m);
    la = m + logf(sum) + ell[f * 4096 + b * 8 + s];
  }
  float best = -1e30f; int bi = 0;
#pragma unroll
  for (int i = 0; i < 8; ++i) {
    float o = __shfl(la, i, 8);
    if (o > best) { best = o; bi = i; }   // first-max rule
  }
  if (s == 0) s0p[b] = bi;
}

// ---------------------------------------------------------------------------
// AR prediction: block per b, exact f32 (matches reference when states match)
// ---------------------------------------------------------------------------
__global__ __launch_bounds__(256) void pred_kernel(const float* __restrict__ emis,
                                                   const float* __restrict__ W,
                                                   const float* __restrict__ means,
                                                   float* __restrict__ ws,
                                                   float* __restrict__ out) {
  const int* chain = (const int*)(ws + OFF_CHAIN);
  const int* s0p   = (const int*)(ws + OFF_S0);
  int b = blockIdx.x, tid = threadIdx.x;
  __shared__ float buf[128][17];       // circular lag buffer
  __shared__ float partial[16][17];
  __shared__ int s0s;
  for (int idx = tid; idx < 2048; idx += 256)
    buf[idx >> 4][idx & 15] = emis[(b << 11) + idx];
  if (tid == 0) s0s = s0p[b];
  __syncthreads();

  int g = tid >> 4, d = tid & 15;
  int start = 0;
  for (int k = 0; k < 16; ++k) {
    int st = chain[s0s * 16 + k];
    const float* Wst = W + st * 32768;
    float p = 0.f;
#pragma unroll
    for (int j = 0; j < 8; ++j) {
      int l = g * 8 + j;
      int row = (start + l) & 127;
      const float* wl = Wst + l * 256 + d;
#pragma unroll
      for (int c = 0; c < 16; ++c) p += buf[row][c] * wl[c * 16];
    }
    partial[g][d] = p;
    __syncthreads();
    if (tid < 16) {
      float v = means[st * 16 + tid];
#pragma unroll
      for (int gg = 0; gg < 16; ++gg) v += partial[gg][tid];
      out[b * 256 + k * 16 + tid] = v;
      buf[start][tid] = v;            // overwrite oldest -> becomes newest
    }
    __syncthreads();
    start = (start + 1) & 127;
  }
}

extern "C" void kernel_launch(void* const* d_in, const int* in_sizes, int n_in,
                              void* d_out, int out_size, void* d_ws, size_t ws_size,
                              hipStream_t stream) {
  const float* emis  = (const float*)d_in[0];
  const float* tmat  = (const float*)d_in[1];
  const float* initd = (const float*)d_in[2];
  const float* means = (const float*)d_in[3];
  const float* cc    = (const float*)d_in[4];
  const float* W     = (const float*)d_in[5];
  float* ws  = (float*)d_ws;
  float* out = (float*)d_out;

  hipLaunchKernelGGL(prep_kernel, dim3(1), dim3(256), 0, stream, tmat, initd, cc, ws);
  hipLaunchKernelGGL(wt_kernel, dim3(1024), dim3(256), 0, stream, W, ws);
  hipLaunchKernelGGL(emis_kernel, dim3(4096), dim3(256), 0, stream, emis, means, ws);
  hipLaunchKernelGGL(fwd_kernel, dim3(16), dim3(256), 0, stream, ws);
  hipLaunchKernelGGL(pred_kernel, dim3(512), dim3(256), 0, stream, emis, W, means, ws, out);
}

// Round 3
// 124.319 us; speedup vs baseline: 1.4065x; 1.4065x over previous
//
#include <hip/hip_runtime.h>
#include <hip/hip_bf16.h>

#define LOG2PI_F 1.8378770664093453f
#define LOG2E_F  1.44269504f

typedef float f32x4 __attribute__((ext_vector_type(4)));
typedef short s16x8 __attribute__((ext_vector_type(8)));
typedef unsigned short u16;

// ---- workspace layout (float offsets into d_ws) ----
#define OFF_PREC   0        // f32 [8][16][16]
#define OFF_LOGDET 2048     // f32 [8]
#define OFF_LTR    2064     // f32 [8][8]   log(softmax(T)+1e-8) * log2e
#define OFF_LINI   2128     // f32 [8]      log softmax(init)    * log2e
#define OFF_CHAIN  2144     // int [8][16]
#define OFF_S0     2304     // int [512]
#define OFF_ELL    4096     // f32 [128][512][8]  (scaled by log2e)
#define OFF_WT     528384   // u16(bf16) [8][128][16][16]  Wt[s][l][d][c]

__device__ inline u16 f2bf(float x) {
  union { float f; unsigned u; } v; v.f = x;
  unsigned r = v.u + 0x7fffu + ((v.u >> 16) & 1u);  // RNE
  return (u16)(r >> 16);
}
__device__ inline float bf2f(short x) {
  return __uint_as_float(((unsigned)(u16)x) << 16);
}

// ---------------------------------------------------------------------------
// kernel 1: blocks 0..1023 build Wt (bf16 transpose); block 1024 does prep
// ---------------------------------------------------------------------------
__global__ __launch_bounds__(256) void prep_wt_kernel(const float* __restrict__ tmat,
                                                      const float* __restrict__ initd,
                                                      const float* __restrict__ cc,
                                                      const float* __restrict__ W,
                                                      float* __restrict__ ws) {
  __shared__ float Ls[8][16][16];
  __shared__ float Cv[8][16][16];
  __shared__ float tmp[256];
  int t = threadIdx.x;

  if (blockIdx.x < 1024) {                       // ---- Wt build ----
    u16* Wt = (u16*)(ws + OFF_WT);
    int sl = blockIdx.x;
    tmp[t] = W[sl * 256 + t];
    __syncthreads();
    int d = t >> 4, c = t & 15;
    Wt[sl * 256 + t] = f2bf(tmp[c * 16 + d]);    // [d][c] = in[c][d]
    return;
  }

  // ---- prep ----
  float* prec   = ws + OFF_PREC;
  float* logdet = ws + OFF_LOGDET;
  float* ltr    = ws + OFF_LTR;
  float* lini   = ws + OFF_LINI;
  int*   chain  = (int*)(ws + OFF_CHAIN);

  // phase 0: chol = tril(cc,-1) + diag(exp(diag))  (128 threads: s,i)
  if (t < 128) {
    int s = t >> 4, i = t & 15;
    const float* c0 = cc + s * 256 + i * 16;
    for (int j = 0; j < 16; ++j) {
      float v = c0[j];
      Ls[s][i][j] = (i > j) ? v : (i == j ? expf(v) : 0.f);
    }
  }
  __syncthreads();
  // phase 1: covar = chol@chol^T + 1e-6 I  (row i per thread)
  if (t < 128) {
    int s = t >> 4, i = t & 15;
    for (int j = 0; j <= i; ++j) {
      float sum = (i == j) ? 1e-6f : 0.f;
      for (int k = 0; k <= j; ++k) sum += Ls[s][i][k] * Ls[s][j][k];
      Cv[s][i][j] = sum; Cv[s][j][i] = sum;
    }
  }
  __syncthreads();
  // phase 2
  if (t < 8) {                                   // cholesky of covar -> Ls
    int s = t;
    for (int j = 0; j < 16; ++j) {
      float dv = Cv[s][j][j];
      for (int k = 0; k < j; ++k) dv -= Ls[s][j][k] * Ls[s][j][k];
      dv = sqrtf(dv);
      Ls[s][j][j] = dv;
      for (int i = j + 1; i < 16; ++i) {
        float v = Cv[s][i][j];
        for (int k = 0; k < j; ++k) v -= Ls[s][i][k] * Ls[s][j][k];
        Ls[s][i][j] = v / dv;
      }
    }
    float ld = 0.f;
    for (int j = 0; j < 16; ++j) ld += logf(Ls[s][j][j]);
    logdet[s] = 2.f * ld;
  } else if (t == 8) {
    float m = -1e30f;
    for (int i = 0; i < 8; ++i) m = fmaxf(m, initd[i]);
    float sum = 0.f;
    for (int i = 0; i < 8; ++i) sum += expf(initd[i] - m);
    float ls = logf(sum);
    for (int i = 0; i < 8; ++i) lini[i] = (initd[i] - m - ls) * LOG2E_F;
  } else if (t == 9) {
    int nxt[8];
    for (int i = 0; i < 8; ++i) {
      float best = -1e30f; int bi = 0;
      for (int j = 0; j < 8; ++j) {
        float v = tmat[i * 8 + j];
        if (v > best) { best = v; bi = j; }
      }
      nxt[i] = bi;
    }
    for (int s0 = 0; s0 < 8; ++s0) {
      int c = s0;
      for (int k = 0; k < 16; ++k) { c = nxt[c]; chain[s0 * 16 + k] = c; }
    }
  } else if (t >= 16 && t < 24) {
    int i = t - 16;
    float m = -1e30f;
    for (int j = 0; j < 8; ++j) m = fmaxf(m, tmat[i * 8 + j]);
    float sum = 0.f;
    for (int j = 0; j < 8; ++j) sum += expf(tmat[i * 8 + j] - m);
    for (int j = 0; j < 8; ++j)
      ltr[i * 8 + j] = logf(expf(tmat[i * 8 + j] - m) / sum + 1e-8f) * LOG2E_F;
  }
  __syncthreads();
  // phase 3: prec = inv(covar) via triangular solves (s,col per thread)
  if (t < 128) {
    int s = t >> 4, col = t & 15;
    float y[16], x[16];
#pragma unroll
    for (int i = 0; i < 16; ++i) {
      float v = (i == col) ? 1.f : 0.f;
#pragma unroll
      for (int k = 0; k < 16; ++k) if (k < i) v -= Ls[s][i][k] * y[k];
      y[i] = v / Ls[s][i][i];
    }
#pragma unroll
    for (int i = 15; i >= 0; --i) {
      float v = y[i];
#pragma unroll
      for (int k = 0; k < 16; ++k) if (k > i) v -= Ls[s][k][i] * x[k];
      x[i] = v / Ls[s][i][i];
    }
#pragma unroll
    for (int i = 0; i < 16; ++i) prec[s * 256 + i * 16 + col] = x[i];
  }
}

// ---------------------------------------------------------------------------
// emis: block = (state-pair sp, batch-group of 4). 4 waves; wave w owns
// m-tiles {w, 7-w}; acc[2 states][4 batches][2 tiles]. A from swizzled LDS
// (one read feeds 2 MFMAs), B from global (one load feeds 4 batches).
// ---------------------------------------------------------------------------
__global__ __launch_bounds__(256, 2) void emis_kernel(const float* __restrict__ emis,
                                                      const float* __restrict__ means,
                                                      float* __restrict__ ws) {
  const float* prec   = ws + OFF_PREC;
  const float* logdet = ws + OFF_LOGDET;
  const u16* Wt = (const u16*)(ws + OFF_WT);
  float* ell = ws + OFF_ELL;

  int sp = blockIdx.x & 3;          // state pair
  int bg = blockIdx.x >> 2;         // batch group (0..127)
  int s0 = sp * 2;
  int bb0 = bg * 4;                 // batch base
  int tid = threadIdx.x;

  __shared__ u16  padh[4][256][16];   // 32 KB, XOR-swizzled 16B slots
  __shared__ float diffL[4][128][20]; // 40 KB, 80B row stride

  char* pbase = (char*)&padh[0][0][0];
  const s16x8 zero8 = {0, 0, 0, 0, 0, 0, 0, 0};

  // zero rows 0..127 of each batch plane (swizzle is closed within the region)
  for (int i = tid; i < 1024; i += 256)
    *(s16x8*)(pbase + (i >> 8) * 8192 + (i & 255) * 16) = zero8;
  // stage emissions (rows 128..255), bf16, swizzled
  for (int i = tid; i < 1024; i += 256) {
    int g = i >> 8, erow = (i >> 1) & 127, h = i & 1;
    const f32x4* src = (const f32x4*)(emis + (size_t)(bb0 + g) * 2048 + erow * 16 + h * 8);
    f32x4 v0 = src[0], v1 = src[1];
    s16x8 pk;
#pragma unroll
    for (int c = 0; c < 4; ++c) { pk[c] = (short)f2bf(v0[c]); pk[c + 4] = (short)f2bf(v1[c]); }
    int row = 128 + erow;
    int off = ((row << 5) + (h << 4)) ^ (((row >> 2) & 3) << 4);
    *(s16x8*)(pbase + g * 8192 + off) = pk;
  }
  __syncthreads();

  int wave = tid >> 6, lane = tid & 63;
  int rc = lane & 15;               // A row-in-tile == C col (d)
  int h  = (lane >> 4) & 1;         // c half
  int dl = lane >> 5;               // which lag of the 32-k step
  int hh = h << 4;
  int m1 = wave, m2 = 7 - wave;
  int k1 = 56 - 8 * m1, k2 = 56 - 8 * m2;   // k2 <= k1
  int r01 = m1 * 16 + rc + dl, r02 = m2 * 16 + rc + dl;

  const u16* Bb0 = Wt + ((size_t)((s0 * 128 + dl) * 16 + rc) * 16) + h * 8 + (size_t)k2 * 512;
  const u16* Bb1 = Bb0 + 32768;

  f32x4 acc[2][4][2] = {};

  s16x8 w0 = *(const s16x8*)Bb0, w1 = *(const s16x8*)Bb1;
  int kk = k2;
  for (; kk < k1; ++kk) {           // only tile m2
    s16x8 n0, n1;
    if (kk < 63) { n0 = *(const s16x8*)(Bb0 + 512); n1 = *(const s16x8*)(Bb1 + 512); }
    Bb0 += 512; Bb1 += 512;
    int row2 = r02 + 2 * kk;
    const char* pa = pbase + (((row2 << 5) + hh) ^ (((row2 >> 2) & 3) << 4));
#pragma unroll
    for (int g = 0; g < 4; ++g) {
      s16x8 a = *(const s16x8*)(pa + g * 8192);
      acc[0][g][0] = __builtin_amdgcn_mfma_f32_16x16x32_bf16(a, w0, acc[0][g][0], 0, 0, 0);
      acc[1][g][0] = __builtin_amdgcn_mfma_f32_16x16x32_bf16(a, w1, acc[1][g][0], 0, 0, 0);
    }
    w0 = n0; w1 = n1;
  }
  for (; kk < 64; ++kk) {           // both tiles
    s16x8 n0, n1;
    if (kk < 63) { n0 = *(const s16x8*)(Bb0 + 512); n1 = *(const s16x8*)(Bb1 + 512); }
    Bb0 += 512; Bb1 += 512;
    int row2 = r02 + 2 * kk, row1 = r01 + 2 * kk;
    const char* pa2 = pbase + (((row2 << 5) + hh) ^ (((row2 >> 2) & 3) << 4));
    const char* pa1 = pbase + (((row1 << 5) + hh) ^ (((row1 >> 2) & 3) << 4));
#pragma unroll
    for (int g = 0; g < 4; ++g) {
      s16x8 a2 = *(const s16x8*)(pa2 + g * 8192);
      acc[0][g][0] = __builtin_amdgcn_mfma_f32_16x16x32_bf16(a2, w0, acc[0][g][0], 0, 0, 0);
      acc[1][g][0] = __builtin_amdgcn_mfma_f32_16x16x32_bf16(a2, w1, acc[1][g][0], 0, 0, 0);
      s16x8 a1 = *(const s16x8*)(pa1 + g * 8192);
      acc[0][g][1] = __builtin_amdgcn_mfma_f32_16x16x32_bf16(a1, w0, acc[0][g][1], 0, 0, 0);
      acc[1][g][1] = __builtin_amdgcn_mfma_f32_16x16x32_bf16(a1, w1, acc[1][g][1], 0, 0, 0);
    }
    w0 = n0; w1 = n1;
  }

  // diff + quad, one state at a time (diffL reused)
  int hi = (lane >> 4) & 3;
#pragma unroll
  for (int s = 0; s < 2; ++s) {
    float mn = means[(s0 + s) * 16 + rc];
#pragma unroll
    for (int tt = 0; tt < 2; ++tt) {
      int m = tt ? m1 : m2;
#pragma unroll
      for (int g = 0; g < 4; ++g) {
#pragma unroll
        for (int r = 0; r < 4; ++r) {
          int f = m * 16 + hi * 4 + r;
          diffL[g][f][rc] =
            emis[(size_t)(bb0 + g) * 2048 + f * 16 + rc] - acc[s][g][tt][r] - mn;
        }
      }
    }
    __syncthreads();
    const float* P = prec + (s0 + s) * 256;     // block-uniform -> scalar loads
    float c2 = -0.72134752f * (logdet[s0 + s] + 16.f * LOG2PI_F);
#pragma unroll
    for (int it = 0; it < 2; ++it) {
      int task = tid + it * 256;
      int g = task >> 7, f = task & 127;
      float dv[16];
#pragma unroll
      for (int c = 0; c < 4; ++c)
        *(f32x4*)&dv[c * 4] = *(const f32x4*)&diffL[g][f][c * 4];
      float qq = 0.f;                            // = quad/2
#pragma unroll
      for (int c = 0; c < 16; ++c) {
        float tsum = 0.5f * P[c * 16 + c] * dv[c];
#pragma unroll
        for (int d = 0; d < 16; ++d)
          if (d > c) tsum = fmaf(P[c * 16 + d], dv[d], tsum);
        qq = fmaf(dv[c], tsum, qq);
      }
      ell[(size_t)f * 4096 + (bb0 + g) * 8 + s0 + s] = fmaf(-2.f * 0.72134752f, qq, c2);
    }
    if (s == 0) __syncthreads();
  }
}

// ---------------------------------------------------------------------------
// forward scan + argmax (base-2 log space; ell/lini/ltr pre-scaled by log2e)
// ---------------------------------------------------------------------------
__global__ __launch_bounds__(64) void fwd_kernel(float* __restrict__ ws) {
  const float* ell  = ws + OFF_ELL;
  const float* ltr  = ws + OFF_LTR;
  const float* lini = ws + OFF_LINI;
  int* s0p = (int*)(ws + OFF_S0);
  int g = blockIdx.x * 64 + threadIdx.x;
  int b = g >> 3, s = g & 7;
  float ltc[8];
#pragma unroll
  for (int i = 0; i < 8; ++i) ltc[i] = ltr[i * 8 + s];
  float la = lini[s] + ell[b * 8 + s];
  for (int f = 1; f < 128; ++f) {
    float e = ell[(size_t)f * 4096 + b * 8 + s];   // independent of chain -> hoists
    float v[8], m = -1e30f;
#pragma unroll
    for (int i = 0; i < 8; ++i) {
      v[i] = __shfl(la, i, 8) + ltc[i];
      m = fmaxf(m, v[i]);
    }
    float sum = 0.f;
#pragma unroll
    for (int i = 0; i < 8; ++i) sum += exp2f(v[i] - m);
    la = m + log2f(sum) + e;
  }
  float best = -1e30f; int bi = 0;
#pragma unroll
  for (int i = 0; i < 8; ++i) {
    float o = __shfl(la, i, 8);
    if (o > best) { best = o; bi = i; }
  }
  if (s == 0) s0p[b] = bi;
}

// ---------------------------------------------------------------------------
// AR prediction: block per b, bf16 weights (Wt), f32 accumulation
// ---------------------------------------------------------------------------
__global__ __launch_bounds__(256) void pred_kernel(const float* __restrict__ emis,
                                                   const float* __restrict__ means,
                                                   float* __restrict__ ws,
                                                   float* __restrict__ out) {
  const int* chain = (const int*)(ws + OFF_CHAIN);
  const int* s0p   = (const int*)(ws + OFF_S0);
  const u16* Wt = (const u16*)(ws + OFF_WT);
  int b = blockIdx.x, tid = threadIdx.x;
  __shared__ float buf[128][20];       // circular lag buffer, 80B row stride
  __shared__ float partial[16][17];
  __shared__ int s0s;
  {
    int row = tid >> 1, hf = tid & 1;
    const f32x4* src = (const f32x4*)(emis + (size_t)b * 2048 + row * 16 + hf * 8);
    *(f32x4*)&buf[row][hf * 8]     = src[0];
    *(f32x4*)&buf[row][hf * 8 + 4] = src[1];
  }
  if (tid == 0) s0s = s0p[b];
  __syncthreads();

  int g = tid >> 4, d = tid & 15;
  int start = 0;
  for (int k = 0; k < 16; ++k) {
    int st = chain[s0s * 16 + k];
    const u16* Wp = Wt + (size_t)st * 32768 + (g * 8) * 256 + d * 16;
    float p = 0.f;
#pragma unroll
    for (int j = 0; j < 8; ++j) {
      int row = (start + g * 8 + j) & 127;
      f32x4 e0 = *(const f32x4*)&buf[row][0];
      f32x4 e1 = *(const f32x4*)&buf[row][4];
      f32x4 e2 = *(const f32x4*)&buf[row][8];
      f32x4 e3 = *(const f32x4*)&buf[row][12];
      s16x8 wa = *(const s16x8*)(Wp + j * 256);
      s16x8 wb = *(const s16x8*)(Wp + j * 256 + 8);
#pragma unroll
      for (int c = 0; c < 4; ++c) {
        p = fmaf(e0[c], bf2f(wa[c]), p);
        p = fmaf(e1[c], bf2f(wa[c + 4]), p);
        p = fmaf(e2[c], bf2f(wb[c]), p);
        p = fmaf(e3[c], bf2f(wb[c + 4]), p);
      }
    }
    partial[g][d] = p;
    __syncthreads();
    if (tid < 16) {
      float v = means[st * 16 + tid];
#pragma unroll
      for (int gg = 0; gg < 16; ++gg) v += partial[gg][tid];
      out[b * 256 + k * 16 + tid] = v;
      buf[start][tid] = v;
    }
    __syncthreads();
    start = (start + 1) & 127;
  }
}

extern "C" void kernel_launch(void* const* d_in, const int* in_sizes, int n_in,
                              void* d_out, int out_size, void* d_ws, size_t ws_size,
                              hipStream_t stream) {
  const float* emis  = (const float*)d_in[0];
  const float* tmat  = (const float*)d_in[1];
  const float* initd = (const float*)d_in[2];
  const float* means = (const float*)d_in[3];
  const float* cc    = (const float*)d_in[4];
  const float* W     = (const float*)d_in[5];
  float* ws  = (float*)d_ws;
  float* out = (float*)d_out;

  hipLaunchKernelGGL(prep_wt_kernel, dim3(1025), dim3(256), 0, stream, tmat, initd, cc, W, ws);
  hipLaunchKernelGGL(emis_kernel, dim3(512), dim3(256), 0, stream, emis, means, ws);
  hipLaunchKernelGGL(fwd_kernel, dim3(64), dim3(64), 0, stream, ws);
  hipLaunchKernelGGL(pred_kernel, dim3(512), dim3(256), 0, stream, emis, means, ws, out);
}